// Round 3
// baseline (268.257 us; speedup 1.0000x reference)
//
#include <hip/hip_runtime.h>
#include <math.h>

// Quantized causal attention on int8 MFMA — R9.
// R8 post-mortem: LDS 44.5KB permits 3 blocks/CU (R7 proved it at VGPR 84),
// but occupancy stayed 20.5% (2 blocks). gfx950 unified VGPR/AGPR file:
// at launch_bounds(256,2) the compiler's budget is 256 total regs, and
// VGPR+AGPR exceeded 170 = floor(512/3) -> capped at 2 waves/SIMD.
// R9: launch_bounds(256,3) (forces total<=170) + register-pressure cuts so
// it fits WITHOUT the scratch spills that killed R7:
//  1. P2 Q-fragments un-hoisted: read 2-at-a-time from q8s LDS inside the
//     cb loop (peak -24..30 regs; +16 ds_read_b128/tile, hidden at 3 waves).
//  2. P1 sarr[8][4] -> [4][4]: stats update per 4-subtile chunk (-16 regs,
//     +8 exp2/tile).
//  3. fminf min-tracking only where pmin is consumed (non-causal or the
//     qt==31 block) — block-uniform branch.
// Tripwire: WRITE_SIZE must stay ~32.8MB. If it balloons -> spills -> revert
// bound to (256,2) next round but keep the pressure cuts.

#define S_LEN 2048
#define BATCH 2
#define NH    16
#define HD    128
#define RSTR  4096   // floats between seq positions
#define SCALE2 (0.08838834764831845f * 1.4426950408889634f)   // (1/sqrt(128))/ln2
#define EXP2F(x) __builtin_amdgcn_exp2f(x)

typedef int v4i __attribute__((ext_vector_type(4)));
#define MFMA16(a,b,c) __builtin_amdgcn_mfma_i32_16x16x64_i8((a),(b),(c),0,0,0)

// ws byte offsets (total ~16.8 MB)
#define WS_K8   0u
#define WS_V8T  (8u*1024u*1024u)
#define WS_SQ   (16u*1024u*1024u)
#define WS_SK   (WS_SQ + 256u*1024u)
#define WS_GSV  (WS_SK + 256u*1024u)

__device__ __forceinline__ int sbsum(unsigned p) {
    return (int)(signed char)(p) + (int)(signed char)(p>>8)
         + (int)(signed char)(p>>16) + (int)(signed char)(p>>24);
}

// ---- fused pre-kernel: V transpose + GSV (blocks 0..511, heavy, FIRST) ----
// ----                   Q/K token sums + K int8 pack (blocks 512..2559)  ----
__global__ __launch_bounds__(256) void prep_pack(
    const float* __restrict__ Q, const float* __restrict__ K, const float* __restrict__ V,
    signed char* __restrict__ K8, float* __restrict__ SQs, float* __restrict__ SKs,
    signed char* __restrict__ V8T, float* __restrict__ GSV)
{
    __shared__ int v8i[128*33];
    const int tid = threadIdx.x;
    const int bx  = blockIdx.x;
    if (bx >= 512) {
        const int base = (bx - 512)*256 + tid;      // 0..524287
        #pragma unroll
        for (int rep = 0; rep < 8; ++rep) {
            const int tensor = rep >> 2;            // 0..3 -> Q, 4..7 -> K
            const int idx = base + (rep & 3)*524288;
            const float* src = tensor ? K : Q;
            int tau = idx >> 5, dg = idx & 31;
            float4 x = *(const float4*)(src + (size_t)tau*128 + 4*dg);
            float ssum = x.x + x.y + x.z + x.w;
            #pragma unroll
            for (int off = 16; off >= 1; off >>= 1) ssum += __shfl_xor(ssum, off);
            if (tensor) {
                int a=(int)x.x, b2=(int)x.y, c=(int)x.z, d=(int)x.w;
                ((int*)K8)[(size_t)tau*32 + dg] = (a&255)|((b2&255)<<8)|((c&255)<<16)|((d&255)<<24);
                if ((tid & 31) == 0) SKs[tau] = ssum;
            } else {
                if ((tid & 31) == 0) SQs[tau] = ssum;
            }
        }
    } else {
        const int bid = bx;
        const int bh = bid & 31, ck = bid >> 5;   // ck = 128-t chunk = v-group
        const int b = bh >> 4, h = bh & 15;
        const int t0 = ck * 128;
        const int boff = b*2048 + h*128;
        #pragma unroll
        for (int it = 0; it < 16; ++it) {
            int idx = tid + it*256;
            int t = idx >> 5, dw = idx & 31;
            float4 x = *(const float4*)(V + (size_t)(t0+t)*RSTR + boff + 4*dw);
            int a=(int)x.x, b2=(int)x.y, c=(int)x.z, d=(int)x.w;
            v8i[t*33 + dw] = (a&255)|((b2&255)<<8)|((c&255)<<16)|((d&255)<<24);
        }
        __syncthreads();
        #pragma unroll
        for (int it = 0; it < 4; ++it) {
            int j = tid + it*256;
            int tg = j & 31, dw = j >> 5;
            unsigned r0 = (unsigned)v8i[(4*tg+0)*33 + dw];
            unsigned r1 = (unsigned)v8i[(4*tg+1)*33 + dw];
            unsigned r2 = (unsigned)v8i[(4*tg+2)*33 + dw];
            unsigned r3 = (unsigned)v8i[(4*tg+3)*33 + dw];
            unsigned x01 = __builtin_amdgcn_perm(r1, r0, 0x05010400u);
            unsigned x23 = __builtin_amdgcn_perm(r3, r2, 0x05010400u);
            unsigned y01 = __builtin_amdgcn_perm(r1, r0, 0x07030602u);
            unsigned y23 = __builtin_amdgcn_perm(r3, r2, 0x07030602u);
            unsigned p[4];
            p[0] = __builtin_amdgcn_perm(x23, x01, 0x05040100u);
            p[1] = __builtin_amdgcn_perm(x23, x01, 0x07060302u);
            p[2] = __builtin_amdgcn_perm(y23, y01, 0x05040100u);
            p[3] = __builtin_amdgcn_perm(y23, y01, 0x07060302u);
            int s[4];
            #pragma unroll
            for (int jj = 0; jj < 4; ++jj) {
                int d = 4*dw + jj;
                *(int*)(V8T + ((size_t)bh*128 + d)*2048 + t0 + 4*tg) = (int)p[jj];
                s[jj] = sbsum(p[jj]);
            }
            #pragma unroll
            for (int off = 1; off < 32; off <<= 1) {
                #pragma unroll
                for (int jj = 0; jj < 4; ++jj) s[jj] += __shfl_xor(s[jj], off);
            }
            if (tg == 0) {
                #pragma unroll
                for (int jj = 0; jj < 4; ++jj)
                    GSV[((size_t)bh*16 + ck)*128 + 4*dw + jj] = (float)s[jj];
            }
        }
    }
}

// ---- main kernel ----
__global__ __launch_bounds__(256, 3) void attn_main(
    const float* __restrict__ Q,
    const signed char* __restrict__ K8, const signed char* __restrict__ V8T,
    const float* __restrict__ QMN, const float* __restrict__ QSC,
    const float* __restrict__ KMN, const float* __restrict__ KSC,
    const float* __restrict__ VMN, const float* __restrict__ VSC,
    const float* __restrict__ SQs, const float* __restrict__ SKs,
    const float* __restrict__ GSV,
    const int* __restrict__ CAUSAL, float* __restrict__ OUT)
{
    __shared__ __align__(16) signed char q8s[64*144];   // [q][d] int8
    __shared__ __align__(16) signed char kv8s[128*144]; // P1: K [t][d] | P2: V [d][t]
    __shared__ __align__(16) signed char pcs[64*144];   // [q][t] code' int8
    __shared__ float rs_c1[64], rs_c2[64], rs_c3[64];
    __shared__ float rs_mx[64], rs_den[64], rs_mn[64];
    __shared__ float rs_u1[64], rs_w1[64], rs_psc[64], rs_pmn[64];
    __shared__ float ktA[2][128], ktB[2][128], ktC[2][128]; // ks*S2, km*S2, sk8
    __shared__ float vsA[128], vsB[128];                // vs, vm (current group)
    __shared__ float vsumL[128], cgsL[128];             // in-block VSUM / CGS row

    signed char* k8s = kv8s;   // Phase-1 alias
    signed char* v8s = kv8s;   // Phase-2 alias

    const int tid  = threadIdx.x;
    const int w    = tid >> 6;
    const int lane = tid & 63;
    const int n    = lane & 15;
    const int quad = lane >> 4;
    const int bhi  = blockIdx.x & 31;
    const int qt   = 31 - (int)(blockIdx.x >> 5);   // heavy tiles first
    const int b    = bhi >> 4, h = bhi & 15;
    const int causal = *CAUSAL;
    const int s0   = qt * 64;
    const int boff = b*2048 + h*128;
    const v4i vzero = {0,0,0,0};
    const v4i ones  = {0x01010101,0x01010101,0x01010101,0x01010101};
    const bool needmn = (!causal) || (qt == 31);   // pmin consumed only here

    // ---- stage Q tile (float -> int8 LDS) + per-row consts ----
    #pragma unroll
    for (int it = 0; it < 8; ++it) {
        int idx = tid + it*256;
        int row = idx >> 5, d4 = (idx & 31) << 2;
        float4 x = *(const float4*)(Q + (size_t)(s0+row)*RSTR + boff + d4);
        int a=(int)x.x, b2=(int)x.y, c=(int)x.z, d=(int)x.w;
        *(int*)(q8s + row*144 + d4) = (a&255)|((b2&255)<<8)|((c&255)<<16)|((d&255)<<24);
    }
    if (tid < 64) {
        int si = (s0 + tid)*32 + bhi;
        float qs = QSC[si], qm = QMN[si];
        rs_c1[tid] = qs; rs_c2[tid] = qm;
        rs_c3[tid] = fmaf(qs, SQs[si], 128.0f*qm);
    }
    __syncthreads();

    const int kt_end = causal ? ((s0 + 63) >> 7) : 15;

    float c1r[4], c2r[4], c3r[4]; int qgr[4];
    #pragma unroll
    for (int r = 0; r < 4; ++r) {
        int qq = 16*w + 4*quad + r;
        c1r[r] = rs_c1[qq]; c2r[r] = rs_c2[qq]; c3r[r] = rs_c3[qq];
        qgr[r] = s0 + qq;
    }
    v4i a0p = *(const v4i*)(q8s + (16*w + n)*144 + 16*quad);
    v4i a1p = *(const v4i*)(q8s + (16*w + n)*144 + 64 + 16*quad);

    float m[4], l[4], mn[4];
    #pragma unroll
    for (int r = 0; r < 4; ++r) { m[r] = -INFINITY; l[r] = 0.f; mn[r] = INFINITY; }

    // ================= Phase 1: softmax stats (log2 domain) =================
    // k8s staged in LDS (2 barriers/tile). Stats updated per 4-subtile chunk
    // so only sarr[4][4] is live (-16 regs vs [8][4]).
#define P1_TILE(MASKED)                                                          \
  do {                                                                           \
    const int t0g = kt * 128;                                                    \
    __syncthreads();                                                             \
    _Pragma("unroll")                                                            \
    for (int it = 0; it < 4; ++it) {                                             \
        int idx = tid + it*256;                                                  \
        int trow = idx >> 3, doff = (idx & 7) << 4;                              \
        *(uint4*)(k8s + trow*144 + doff) =                                       \
            *(const uint4*)(K8 + ((size_t)(t0g+trow)*32 + bhi)*128 + doff);      \
    }                                                                            \
    if (tid < 128) {                                                             \
        int si = (t0g + tid)*32 + bhi;                                           \
        ktA[0][tid] = KSC[si]*SCALE2; ktB[0][tid] = KMN[si]*SCALE2;              \
        ktC[0][tid] = SKs[si];                                                   \
    }                                                                            \
    __syncthreads();                                                             \
    _Pragma("unroll")                                                            \
    for (int half = 0; half < 2; ++half) {                                       \
        float tmax[4], sarr[4][4];                                               \
        _Pragma("unroll")                                                        \
        for (int r = 0; r < 4; ++r) tmax[r] = -INFINITY;                         \
        _Pragma("unroll")                                                        \
        for (int tb4 = 0; tb4 < 4; ++tb4) {                                      \
            int tb = half*4 + tb4;                                               \
            v4i b0 = *(const v4i*)(k8s + (16*tb + n)*144 + 16*quad);             \
            v4i b1 = *(const v4i*)(k8s + (16*tb + n)*144 + 64 + 16*quad);        \
            v4i acc = MFMA16(a0p, b0, vzero);                                    \
            acc = MFMA16(a1p, b1, acc);                                          \
            int tl = 16*tb + n;                                                  \
            float kA = ktA[0][tl], kB = ktB[0][tl], kC = ktC[0][tl];             \
            _Pragma("unroll")                                                    \
            for (int r = 0; r < 4; ++r) {                                        \
                float Sf = (float)acc[r];                                        \
                float sv = fmaf(kA, fmaf(c1r[r], Sf, c2r[r]*kC), kB*c3r[r]);     \
                if (MASKED) sv = (t0g + tl > qgr[r]) ? -INFINITY : sv;           \
                sarr[tb4][r] = sv;                                               \
                tmax[r] = fmaxf(tmax[r], sv);                                    \
                if (needmn) mn[r] = fminf(mn[r], sv);                            \
            }                                                                    \
        }                                                                        \
        _Pragma("unroll")                                                        \
        for (int r = 0; r < 4; ++r) {                                            \
            float mm = fmaxf(m[r], tmax[r]);                                     \
            if (mm > -INFINITY) {                                                \
                float e0 = EXP2F(sarr[0][r]-mm) + EXP2F(sarr[1][r]-mm);          \
                float e1 = EXP2F(sarr[2][r]-mm) + EXP2F(sarr[3][r]-mm);          \
                l[r] = fmaf(l[r], EXP2F(m[r]-mm), e0+e1);                        \
                m[r] = mm;                                                       \
            }                                                                    \
        }                                                                        \
    }                                                                            \
  } while (0)

    {
        int kt;
        for (kt = 0; kt < kt_end; ++kt) P1_TILE(false);
        kt = kt_end;
        if (causal) P1_TILE(true); else P1_TILE(false);
    }

    // reduce stats across the 16 col-lanes
    #pragma unroll
    for (int r = 0; r < 4; ++r) {
        #pragma unroll
        for (int off = 1; off < 16; off <<= 1) {
            float m2 = __shfl_xor(m[r], off);
            float l2 = __shfl_xor(l[r], off);
            float n2 = __shfl_xor(mn[r], off);
            float mm = fmaxf(m[r], m2);
            if (mm > -INFINITY) l[r] = l[r]*EXP2F(m[r]-mm) + l2*EXP2F(m2-mm);
            m[r] = mm;
            mn[r] = fminf(mn[r], n2);
        }
        if (n == 0) {
            int qq = 16*w + 4*quad + r;
            rs_mx[qq] = m[r]; rs_den[qq] = l[r]; rs_mn[qq] = mn[r];
        }
    }
    __syncthreads();   // also: all P1 reads of kv8s (k8s) done before P2 writes
    if (tid < 64) {
        float mx = rs_mx[tid], den = rs_den[tid], mnv = rs_mn[tid];
        float invd = 1.0f/den;
        int s = s0 + tid;
        bool hasmask = (causal != 0) && (s < S_LEN-1);
        float pmin = hasmask ? 0.0f : EXP2F(mnv - mx)*invd;
        float psc  = (invd - pmin)/255.0f + 1e-12f;
        float ipsc = 1.0f/psc;
        rs_u1[tid] = invd*ipsc; rs_w1[tid] = -pmin*ipsc;
        rs_psc[tid] = psc; rs_pmn[tid] = pmin;
    } else if (tid >= 128) {
        // in-block VSUM (full row) + CGS (cumulative to kt_end) for this bh
        int d = tid - 128;
        float vsum = 0.f, cgs = 0.f;
        #pragma unroll
        for (int g = 0; g < 16; ++g) {
            float gs = GSV[((size_t)bhi*16 + g)*128 + d];
            int vi = ((g*BATCH + b)*NH + h)*HD + d;
            float vs = VSC[vi], vm = VMN[vi];
            vsum = fmaf(vs, gs, fmaf(128.0f, vm, vsum));
            if (g <= kt_end) cgs = fmaf(128.0f*vs, gs, fmaf(16384.0f, vm, cgs));
        }
        vsumL[d] = vsum; cgsL[d] = cgs;
        // stage kt=0 consts for Phase 2 double-buffer
        int si = d*32 + bhi;
        ktA[0][d] = KSC[si]*SCALE2; ktB[0][d] = KMN[si]*SCALE2; ktC[0][d] = SKs[si];
    }
    __syncthreads();

    // ---- hoist P2 tile-invariant scalars (Q fragments stay in LDS) ----
    float qc1[4], qc2[4], qc3[4], qmxn[4], qu1[4], qw1[4];
    int qgq[4];
    #pragma unroll
    for (int cb = 0; cb < 4; ++cb) {
        int qcol = 16*cb + n;
        qc1[cb] = rs_c1[qcol]; qc2[cb] = rs_c2[qcol]; qc3[cb] = rs_c3[qcol];
        qmxn[cb] = -rs_mx[qcol]; qu1[cb] = rs_u1[qcol]; qw1[cb] = rs_w1[qcol];
        qgq[cb] = s0 + qcol;
    }

    // ================= Phase 2: requant + PV =================
    float outa[4][8];
    #pragma unroll
    for (int r = 0; r < 4; ++r)
        #pragma unroll
        for (int db = 0; db < 8; ++db) outa[r][db] = 0.f;

    // 2 barriers/tile: {bar; stage v8s + NEXT consts + vsA; requant->pcs
    //                   (uses CUR consts staged last tile); bar; PV}
#define P2_TILE(MASKED)                                                          \
  do {                                                                           \
    const int t0g = kt * 128;                                                    \
    const int cur = kt & 1;                                                      \
    __syncthreads();   /* previous PV reads of v8s/pcs/vsA done */               \
    _Pragma("unroll")                                                            \
    for (int it = 0; it < 4; ++it) {                                             \
        int idx = tid + it*256;                                                  \
        int trow = idx >> 3, doff = (idx & 7) << 4;                              \
        *(uint4*)(v8s + trow*144 + doff) =                                       \
            *(const uint4*)(V8T + ((size_t)bhi*128 + trow)*2048 + t0g + doff);   \
    }                                                                            \
    if (tid < 128) {                                                             \
        if (kt < kt_end) {                                                       \
            int si = (t0g + 128 + tid)*32 + bhi;                                 \
            ktA[cur^1][tid] = KSC[si]*SCALE2;                                    \
            ktB[cur^1][tid] = KMN[si]*SCALE2;                                    \
            ktC[cur^1][tid] = SKs[si];                                           \
        }                                                                        \
    } else {                                                                     \
        int d = tid - 128;                                                       \
        int vi = ((kt*BATCH + b)*NH + h)*HD + d;                                 \
        vsA[d] = VSC[vi]; vsB[d] = VMN[vi];                                      \
    }                                                                            \
    _Pragma("unroll")                                                            \
    for (int rb = 0; rb < 2; ++rb) {                                             \
        int trow = 32*w + 16*rb;                                                 \
        const signed char* kp = K8 + ((size_t)(t0g+trow+n)*32 + bhi)*128         \
                                   + 16*quad;                                    \
        v4i a0 = *(const v4i*)kp;          /* A-operand direct from global */    \
        v4i a1 = *(const v4i*)(kp + 64);                                         \
        float ksr[4], kmr[4], skr[4];                                            \
        int tgb = t0g + trow + 4*quad;                                           \
        _Pragma("unroll")                                                        \
        for (int r = 0; r < 4; ++r) {                                            \
            int tl = trow + 4*quad + r;                                          \
            ksr[r] = ktA[cur][tl]; kmr[r] = ktB[cur][tl]; skr[r] = ktC[cur][tl]; \
        }                                                                        \
        _Pragma("unroll")                                                        \
        for (int cb = 0; cb < 4; ++cb) {                                         \
            v4i qb0 = *(const v4i*)(q8s + (16*cb + n)*144 + 16*quad);            \
            v4i qb1 = *(const v4i*)(q8s + (16*cb + n)*144 + 64 + 16*quad);       \
            v4i acc = MFMA16(a0, qb0, vzero);                                    \
            acc = MFMA16(a1, qb1, acc);                                          \
            int cby[4];                                                          \
            _Pragma("unroll")                                                    \
            for (int r = 0; r < 4; ++r) {                                        \
                float Sf = (float)acc[r];                                        \
                float x = fmaf(ksr[r], fmaf(qc1[cb], Sf, qc2[cb]*skr[r]),        \
                               fmaf(kmr[r], qc3[cb], qmxn[cb]));                 \
                if (MASKED) x = (tgb + r > qgq[cb]) ? -INFINITY : x;             \
                float e = EXP2F(x);                                              \
                float f = fmaf(e, qu1[cb], qw1[cb]) + 8388608.0f; /* RNE int */  \
                cby[r] = __float_as_int(f);                                      \
            }                                                                    \
            unsigned t01 = __builtin_amdgcn_perm((unsigned)cby[1],               \
                                                 (unsigned)cby[0], 0x00000400u); \
            unsigned t23 = __builtin_amdgcn_perm((unsigned)cby[3],               \
                                                 (unsigned)cby[2], 0x04000000u); \
            int packed = (int)(__builtin_amdgcn_perm(t23, t01, 0x07060100u)      \
                               ^ 0x80808080u);  /* code - 128 per byte */        \
            *(int*)(pcs + (16*cb + n)*144 + trow + 4*quad) = packed;             \
        }                                                                        \
    }                                                                            \
    __syncthreads();                                                             \
    {                                                                            \
        v4i a0 = *(const v4i*)(pcs + (16*w + n)*144 + 16*quad);                  \
        v4i a1 = *(const v4i*)(pcs + (16*w + n)*144 + 64 + 16*quad);             \
        v4i c1a = MFMA16(a0, ones, vzero);                                       \
        c1a = MFMA16(a1, ones, c1a);                                             \
        float c1f[4];                                                            \
        _Pragma("unroll")                                                        \
        for (int r = 0; r < 4; ++r) c1f[r] = (float)c1a[r];                      \
        _Pragma("unroll")                                                        \
        for (int db = 0; db < 8; ++db) {                                         \
            v4i b0 = *(const v4i*)(v8s + (16*db + n)*144 + 16*quad);             \
            v4i b1 = *(const v4i*)(v8s + (16*db + n)*144 + 64 + 16*quad);        \
            v4i cv = MFMA16(a0, b0, vzero);                                      \
            cv = MFMA16(a1, b1, cv);                                             \
            int d = 16*db + n;                                                   \
            float vs = vsA[d], vm = vsB[d];                                      \
            _Pragma("unroll")                                                    \
            for (int r = 0; r < 4; ++r)                                          \
                outa[r][db] = fmaf(vs, (float)cv[r],                             \
                                   fmaf(vm, c1f[r], outa[r][db]));               \
        }                                                                        \
    }                                                                            \
  } while (0)

    {
        int kt;
        for (kt = 0; kt < kt_end; ++kt) P2_TILE(false);
        kt = kt_end;
        if (causal) P2_TILE(true); else P2_TILE(false);
    }

    // ---- epilogue: out = psc*(outa + cgs) + pmin*vsum ----
    float pscr[4], pmnr[4];
    #pragma unroll
    for (int r = 0; r < 4; ++r) {
        int qq = 16*w + 4*quad + r;
        pscr[r] = rs_psc[qq]; pmnr[r] = rs_pmn[qq];
    }
    #pragma unroll
    for (int db = 0; db < 8; ++db) {
        int d = 16*db + n;
        float vsum = vsumL[d];
        float cgs  = cgsL[d];
        #pragma unroll
        for (int r = 0; r < 4; ++r) {
            int s = s0 + 16*w + 4*quad + r;
            OUT[(size_t)s*RSTR + boff + d] = fmaf(pscr[r], outa[r][db] + cgs, pmnr[r]*vsum);
        }
    }
}

extern "C" void kernel_launch(void* const* d_in, const int* in_sizes, int n_in,
                              void* d_out, int out_size, void* d_ws, size_t ws_size,
                              hipStream_t stream) {
    (void)in_sizes; (void)n_in; (void)out_size; (void)ws_size;
    const float* Q   = (const float*)d_in[0];
    const float* K   = (const float*)d_in[1];
    const float* V   = (const float*)d_in[2];
    const float* QMN = (const float*)d_in[3];
    const float* QSC = (const float*)d_in[4];
    const float* KMN = (const float*)d_in[5];
    const float* KSC = (const float*)d_in[6];
    const float* VMN = (const float*)d_in[7];
    const float* VSC = (const float*)d_in[8];
    const int*   CS  = (const int*)d_in[9];
    float* out = (float*)d_out;

    char* ws = (char*)d_ws;
    signed char* K8  = (signed char*)(ws + WS_K8);
    signed char* V8T = (signed char*)(ws + WS_V8T);
    float* SQs  = (float*)(ws + WS_SQ);
    float* SKs  = (float*)(ws + WS_SK);
    float* GSVp = (float*)(ws + WS_GSV);

    prep_pack<<<512 + 2048, 256, 0, stream>>>(Q, K, V, K8, SQs, SKs, V8T, GSVp);
    attn_main<<<1024, 256, 0, stream>>>(Q, K8, V8T, QMN, QSC, KMN, KSC, VMN, VSC,
                                        SQs, SKs, GSVp, CS, out);
}

// Round 4
// 253.891 us; speedup vs baseline: 1.0566x; 1.0566x over previous
//
#include <hip/hip_runtime.h>
#include <math.h>

// Quantized causal attention on int8 MFMA — R10.
// R9 post-mortem: forced 3-blocks/CU spilled again (WRITE 32.8->60.9MB,
// FETCH 37->57MB) and lost to the 2-block version. Occupancy axis abandoned;
// kernel needs ~180+ live regs, best measured configs are all (256,2).
// R10 attacks the OTHER half: prep+overhead ~= 130us every round for ~120MB
// of traffic (19us roofline). The off-roofline work is the shuffle-tree
// reductions (SQs/SKs token sums, GSV group sums). All are int8 row-sums =
// one MFMA-with-ones pair on a 9%-utilized MFMA pipe, bit-identical:
//  1. SQs -> MFMA16(a0p/a1p, ones) after Q staging (prep no longer reads Q).
//  2. SKs/ktC -> P1: MFMA16(ones,b) per sub-tile; P2: MFMA16(a,ones) = skr.
//  3. GSV/vsum/cgs -> P2: MFMA16(ones, v-frag) per db; accumulate in regs
//     with identical fmaf ordering (bit-exact).
// prep becomes two pure-streaming kernels (prep_k pack, prep_v transpose),
// split for separate rocprof rows. attn_main structure = R8 (best recent),
// launch_bounds(256,2), no spills (tripwire: WRITE_SIZE ~32.8MB).

#define S_LEN 2048
#define BATCH 2
#define NH    16
#define HD    128
#define RSTR  4096   // floats between seq positions
#define SCALE2 (0.08838834764831845f * 1.4426950408889634f)   // (1/sqrt(128))/ln2
#define EXP2F(x) __builtin_amdgcn_exp2f(x)

typedef int v4i __attribute__((ext_vector_type(4)));
#define MFMA16(a,b,c) __builtin_amdgcn_mfma_i32_16x16x64_i8((a),(b),(c),0,0,0)

// ws byte offsets (16 MB total)
#define WS_K8   0u
#define WS_V8T  (8u*1024u*1024u)

// ---- prep_k: pure streaming float->int8 pack of K (no LDS, no shuffles) ----
__global__ __launch_bounds__(256) void prep_k(const float* __restrict__ K,
                                              signed char* __restrict__ K8)
{
    const int base = blockIdx.x*2048 + threadIdx.x;   // 1024 blocks x 256 x 8
    #pragma unroll
    for (int rep = 0; rep < 8; ++rep) {
        int idx = base + rep*256;                     // float4 index
        float4 x = *(const float4*)(K + (size_t)idx*4);
        int a=(int)x.x, b=(int)x.y, c=(int)x.z, d=(int)x.w;
        ((int*)K8)[idx] = (a&255)|((b&255)<<8)|((c&255)<<16)|((d&255)<<24);
    }
}

// ---- prep_v: V transpose to [bh][d][t] int8 (LDS transpose, no reductions) --
__global__ __launch_bounds__(256) void prep_v(const float* __restrict__ V,
                                              signed char* __restrict__ V8T)
{
    __shared__ int v8i[128*33];
    const int tid = threadIdx.x;
    const int bid = blockIdx.x;                 // 512 blocks
    const int bh = bid & 31, ck = bid >> 5;     // ck = 128-t chunk
    const int b = bh >> 4, h = bh & 15;
    const int t0 = ck * 128;
    const int boff = b*2048 + h*128;
    #pragma unroll
    for (int it = 0; it < 16; ++it) {
        int idx = tid + it*256;
        int t = idx >> 5, dw = idx & 31;
        float4 x = *(const float4*)(V + (size_t)(t0+t)*RSTR + boff + 4*dw);
        int a=(int)x.x, b2=(int)x.y, c=(int)x.z, d=(int)x.w;
        v8i[t*33 + dw] = (a&255)|((b2&255)<<8)|((c&255)<<16)|((d&255)<<24);
    }
    __syncthreads();
    #pragma unroll
    for (int it = 0; it < 4; ++it) {
        int j = tid + it*256;
        int tg = j & 31, dw = j >> 5;
        unsigned r0 = (unsigned)v8i[(4*tg+0)*33 + dw];
        unsigned r1 = (unsigned)v8i[(4*tg+1)*33 + dw];
        unsigned r2 = (unsigned)v8i[(4*tg+2)*33 + dw];
        unsigned r3 = (unsigned)v8i[(4*tg+3)*33 + dw];
        unsigned x01 = __builtin_amdgcn_perm(r1, r0, 0x05010400u);
        unsigned x23 = __builtin_amdgcn_perm(r3, r2, 0x05010400u);
        unsigned y01 = __builtin_amdgcn_perm(r1, r0, 0x07030602u);
        unsigned y23 = __builtin_amdgcn_perm(r3, r2, 0x07030602u);
        unsigned p[4];
        p[0] = __builtin_amdgcn_perm(x23, x01, 0x05040100u);
        p[1] = __builtin_amdgcn_perm(x23, x01, 0x07060302u);
        p[2] = __builtin_amdgcn_perm(y23, y01, 0x05040100u);
        p[3] = __builtin_amdgcn_perm(y23, y01, 0x07060302u);
        #pragma unroll
        for (int jj = 0; jj < 4; ++jj)
            *(int*)(V8T + ((size_t)bh*128 + 4*dw + jj)*2048 + t0 + 4*tg) = (int)p[jj];
    }
}

// ---- main kernel ----
__global__ __launch_bounds__(256, 2) void attn_main(
    const float* __restrict__ Q,
    const signed char* __restrict__ K8, const signed char* __restrict__ V8T,
    const float* __restrict__ QMN, const float* __restrict__ QSC,
    const float* __restrict__ KMN, const float* __restrict__ KSC,
    const float* __restrict__ VMN, const float* __restrict__ VSC,
    const int* __restrict__ CAUSAL, float* __restrict__ OUT)
{
    __shared__ __align__(16) signed char q8s[64*144];   // [q][d] int8
    __shared__ __align__(16) signed char kv8s[128*144]; // P1: K [t][d] | P2: V [d][t]
    __shared__ __align__(16) signed char pcs[64*144];   // [q][t] code' int8
    __shared__ float rs_c1[64], rs_c2[64], rs_c3[64];
    __shared__ float rs_mx[64], rs_den[64], rs_mn[64];
    __shared__ float rs_u1[64], rs_w1[64], rs_psc[64], rs_pmn[64];
    __shared__ float ktA[2][128], ktB[2][128];          // ks*S2, km*S2 (dbuf)
    __shared__ float vsA[128], vsB[128];                // vs, vm (current group)

    signed char* k8s = kv8s;   // Phase-1 alias
    signed char* v8s = kv8s;   // Phase-2 alias

    const int tid  = threadIdx.x;
    const int w    = tid >> 6;
    const int lane = tid & 63;
    const int n    = lane & 15;
    const int quad = lane >> 4;
    const int bhi  = blockIdx.x & 31;
    const int qt   = 31 - (int)(blockIdx.x >> 5);   // heavy tiles first
    const int b    = bhi >> 4, h = bhi & 15;
    const int causal = *CAUSAL;
    const int s0   = qt * 64;
    const int boff = b*2048 + h*128;
    const v4i vzero = {0,0,0,0};
    const v4i ones  = {0x01010101,0x01010101,0x01010101,0x01010101};
    const bool needmn = (!causal) || (qt == 31);   // pmin consumed only here

    // ---- stage Q tile (float -> int8 LDS) + per-row qs/qm consts ----
    #pragma unroll
    for (int it = 0; it < 8; ++it) {
        int idx = tid + it*256;
        int row = idx >> 5, d4 = (idx & 31) << 2;
        float4 x = *(const float4*)(Q + (size_t)(s0+row)*RSTR + boff + d4);
        int a=(int)x.x, b2=(int)x.y, c=(int)x.z, d=(int)x.w;
        *(int*)(q8s + row*144 + d4) = (a&255)|((b2&255)<<8)|((c&255)<<16)|((d&255)<<24);
    }
    if (tid < 64) {
        int si = (s0 + tid)*32 + bhi;
        rs_c1[tid] = QSC[si]; rs_c2[tid] = QMN[si];
    }
    __syncthreads();

    const int kt_end = causal ? ((s0 + 63) >> 7) : 15;

    // Q fragments + Q row-sums via MFMA-ones -> rs_c3 (replaces prep SQs)
    v4i a0p = *(const v4i*)(q8s + (16*w + n)*144 + 16*quad);
    v4i a1p = *(const v4i*)(q8s + (16*w + n)*144 + 64 + 16*quad);
    {
        v4i qsum = MFMA16(a0p, ones, vzero);
        qsum = MFMA16(a1p, ones, qsum);
        if (n == 0) {
            #pragma unroll
            for (int r = 0; r < 4; ++r) {
                int qq = 16*w + 4*quad + r;
                rs_c3[qq] = fmaf(rs_c1[qq], (float)qsum[r], 128.0f*rs_c2[qq]);
            }
        }
    }
    __syncthreads();

    float c1r[4], c2r[4], c3r[4]; int qgr[4];
    #pragma unroll
    for (int r = 0; r < 4; ++r) {
        int qq = 16*w + 4*quad + r;
        c1r[r] = rs_c1[qq]; c2r[r] = rs_c2[qq]; c3r[r] = rs_c3[qq];
        qgr[r] = s0 + qq;
    }

    float m[4], l[4], mn[4];
    #pragma unroll
    for (int r = 0; r < 4; ++r) { m[r] = -INFINITY; l[r] = 0.f; mn[r] = INFINITY; }

    // ================= Phase 1: softmax stats (log2 domain) =================
    // k8s staged in LDS (2 barriers/tile). K row-sum kC via MFMA(ones, b).
#define P1_TILE(MASKED)                                                          \
  do {                                                                           \
    const int t0g = kt * 128;                                                    \
    __syncthreads();                                                             \
    _Pragma("unroll")                                                            \
    for (int it = 0; it < 4; ++it) {                                             \
        int idx = tid + it*256;                                                  \
        int trow = idx >> 3, doff = (idx & 7) << 4;                              \
        *(uint4*)(k8s + trow*144 + doff) =                                       \
            *(const uint4*)(K8 + ((size_t)(t0g+trow)*32 + bhi)*128 + doff);      \
    }                                                                            \
    if (tid < 128) {                                                             \
        int si = (t0g + tid)*32 + bhi;                                           \
        ktA[0][tid] = KSC[si]*SCALE2; ktB[0][tid] = KMN[si]*SCALE2;              \
    }                                                                            \
    __syncthreads();                                                             \
    float tmax[4], sarr[8][4];                                                   \
    _Pragma("unroll")                                                            \
    for (int r = 0; r < 4; ++r) tmax[r] = -INFINITY;                             \
    _Pragma("unroll")                                                            \
    for (int tb = 0; tb < 8; ++tb) {                                             \
        v4i b0 = *(const v4i*)(k8s + (16*tb + n)*144 + 16*quad);                 \
        v4i b1 = *(const v4i*)(k8s + (16*tb + n)*144 + 64 + 16*quad);            \
        v4i acc = MFMA16(a0p, b0, vzero);                                        \
        acc = MFMA16(a1p, b1, acc);                                              \
        v4i acc1 = MFMA16(ones, b0, vzero);                                      \
        acc1 = MFMA16(ones, b1, acc1);                                           \
        int tl = 16*tb + n;                                                      \
        float kA = ktA[0][tl], kB = ktB[0][tl], kC = (float)acc1[0];             \
        _Pragma("unroll")                                                        \
        for (int r = 0; r < 4; ++r) {                                            \
            float Sf = (float)acc[r];                                            \
            float sv = fmaf(kA, fmaf(c1r[r], Sf, c2r[r]*kC), kB*c3r[r]);         \
            if (MASKED) sv = (t0g + tl > qgr[r]) ? -INFINITY : sv;               \
            sarr[tb][r] = sv;                                                    \
            tmax[r] = fmaxf(tmax[r], sv);                                        \
            if (needmn) mn[r] = fminf(mn[r], sv);                                \
        }                                                                        \
    }                                                                            \
    _Pragma("unroll")                                                            \
    for (int r = 0; r < 4; ++r) {                                                \
        float mm = fmaxf(m[r], tmax[r]);                                         \
        if (mm > -INFINITY) {                                                    \
            float e0 = EXP2F(sarr[0][r]-mm) + EXP2F(sarr[1][r]-mm);              \
            float e1 = EXP2F(sarr[2][r]-mm) + EXP2F(sarr[3][r]-mm);              \
            float e2 = EXP2F(sarr[4][r]-mm) + EXP2F(sarr[5][r]-mm);              \
            float e3 = EXP2F(sarr[6][r]-mm) + EXP2F(sarr[7][r]-mm);              \
            l[r] = fmaf(l[r], EXP2F(m[r]-mm), (e0+e1)+(e2+e3));                  \
            m[r] = mm;                                                           \
        }                                                                        \
    }                                                                            \
  } while (0)

    {
        int kt;
        for (kt = 0; kt < kt_end; ++kt) P1_TILE(false);
        kt = kt_end;
        if (causal) P1_TILE(true); else P1_TILE(false);
    }

    // reduce stats across the 16 col-lanes
    #pragma unroll
    for (int r = 0; r < 4; ++r) {
        #pragma unroll
        for (int off = 1; off < 16; off <<= 1) {
            float m2 = __shfl_xor(m[r], off);
            float l2 = __shfl_xor(l[r], off);
            float n2 = __shfl_xor(mn[r], off);
            float mm = fmaxf(m[r], m2);
            if (mm > -INFINITY) l[r] = l[r]*EXP2F(m[r]-mm) + l2*EXP2F(m2-mm);
            m[r] = mm;
            mn[r] = fminf(mn[r], n2);
        }
        if (n == 0) {
            int qq = 16*w + 4*quad + r;
            rs_mx[qq] = m[r]; rs_den[qq] = l[r]; rs_mn[qq] = mn[r];
        }
    }
    __syncthreads();   // also: all P1 reads of kv8s (k8s) done before P2 writes
    if (tid < 64) {
        float mx = rs_mx[tid], den = rs_den[tid], mnv = rs_mn[tid];
        float invd = 1.0f/den;
        int s = s0 + tid;
        bool hasmask = (causal != 0) && (s < S_LEN-1);
        float pmin = hasmask ? 0.0f : EXP2F(mnv - mx)*invd;
        float psc  = (invd - pmin)/255.0f + 1e-12f;
        float ipsc = 1.0f/psc;
        rs_u1[tid] = invd*ipsc; rs_w1[tid] = -pmin*ipsc;
        rs_psc[tid] = psc; rs_pmn[tid] = pmin;
    } else if (tid >= 128) {
        // stage kt=0 consts for Phase 2 double-buffer
        int d = tid - 128;
        int si = d*32 + bhi;
        ktA[0][d] = KSC[si]*SCALE2; ktB[0][d] = KMN[si]*SCALE2;
    }
    __syncthreads();

    // ---- hoist P2 tile-invariants: Q B-fragments + per-q constants ----
    v4i qb0[4], qb1[4];
    float qc1[4], qc2[4], qc3[4], qmxn[4], qu1[4], qw1[4];
    int qgq[4];
    #pragma unroll
    for (int cb = 0; cb < 4; ++cb) {
        int qcol = 16*cb + n;
        qb0[cb] = *(const v4i*)(q8s + qcol*144 + 16*quad);
        qb1[cb] = *(const v4i*)(q8s + qcol*144 + 64 + 16*quad);
        qc1[cb] = rs_c1[qcol]; qc2[cb] = rs_c2[qcol]; qc3[cb] = rs_c3[qcol];
        qmxn[cb] = -rs_mx[qcol]; qu1[cb] = rs_u1[qcol]; qw1[cb] = rs_w1[qcol];
        qgq[cb] = s0 + qcol;
    }

    // ================= Phase 2: requant + PV =================
    float outa[4][8];
    float cgsr[8], vsr[8];   // per-tile accumulated CGS / VSUM rows (reg)
    #pragma unroll
    for (int db = 0; db < 8; ++db) { cgsr[db] = 0.f; vsr[db] = 0.f; }
    #pragma unroll
    for (int r = 0; r < 4; ++r)
        #pragma unroll
        for (int db = 0; db < 8; ++db) outa[r][db] = 0.f;

    // 2 barriers/tile: {bar; stage v8s + NEXT ktA/B + vsA/B; requant->pcs
    //                   (skr via MFMA(a,ones)); bar; PV + gsum via MFMA(ones,b)}
#define P2_TILE(MASKED)                                                          \
  do {                                                                           \
    const int t0g = kt * 128;                                                    \
    const int cur = kt & 1;                                                      \
    __syncthreads();   /* previous PV reads of v8s/pcs/vsA done */               \
    _Pragma("unroll")                                                            \
    for (int it = 0; it < 4; ++it) {                                             \
        int idx = tid + it*256;                                                  \
        int trow = idx >> 3, doff = (idx & 7) << 4;                              \
        *(uint4*)(v8s + trow*144 + doff) =                                       \
            *(const uint4*)(V8T + ((size_t)bhi*128 + trow)*2048 + t0g + doff);   \
    }                                                                            \
    if (tid < 128) {                                                             \
        if (kt < kt_end) {                                                       \
            int si = (t0g + 128 + tid)*32 + bhi;                                 \
            ktA[cur^1][tid] = KSC[si]*SCALE2;                                    \
            ktB[cur^1][tid] = KMN[si]*SCALE2;                                    \
        }                                                                        \
    } else {                                                                     \
        int d = tid - 128;                                                       \
        int vi = ((kt*BATCH + b)*NH + h)*HD + d;                                 \
        vsA[d] = VSC[vi]; vsB[d] = VMN[vi];                                      \
    }                                                                            \
    _Pragma("unroll")                                                            \
    for (int rb = 0; rb < 2; ++rb) {                                             \
        int trow = 32*w + 16*rb;                                                 \
        const signed char* kp = K8 + ((size_t)(t0g+trow+n)*32 + bhi)*128         \
                                   + 16*quad;                                    \
        v4i a0 = *(const v4i*)kp;          /* A-operand direct from global */    \
        v4i a1 = *(const v4i*)(kp + 64);                                         \
        v4i accK = MFMA16(a0, ones, vzero);   /* K row-sums = skr */             \
        accK = MFMA16(a1, ones, accK);                                           \
        float ksr[4], kmr[4], skr[4];                                            \
        int tgb = t0g + trow + 4*quad;                                           \
        _Pragma("unroll")                                                        \
        for (int r = 0; r < 4; ++r) {                                            \
            int tl = trow + 4*quad + r;                                          \
            ksr[r] = ktA[cur][tl]; kmr[r] = ktB[cur][tl];                        \
            skr[r] = (float)accK[r];                                             \
        }                                                                        \
        _Pragma("unroll")                                                        \
        for (int cb = 0; cb < 4; ++cb) {                                         \
            v4i acc = MFMA16(a0, qb0[cb], vzero);                                \
            acc = MFMA16(a1, qb1[cb], acc);                                      \
            int cby[4];                                                          \
            _Pragma("unroll")                                                    \
            for (int r = 0; r < 4; ++r) {                                        \
                float Sf = (float)acc[r];                                        \
                float x = fmaf(ksr[r], fmaf(qc1[cb], Sf, qc2[cb]*skr[r]),        \
                               fmaf(kmr[r], qc3[cb], qmxn[cb]));                 \
                if (MASKED) x = (tgb + r > qgq[cb]) ? -INFINITY : x;             \
                float e = EXP2F(x);                                              \
                float f = fmaf(e, qu1[cb], qw1[cb]) + 8388608.0f; /* RNE int */  \
                cby[r] = __float_as_int(f);                                      \
            }                                                                    \
            unsigned t01 = __builtin_amdgcn_perm((unsigned)cby[1],               \
                                                 (unsigned)cby[0], 0x00000400u); \
            unsigned t23 = __builtin_amdgcn_perm((unsigned)cby[3],               \
                                                 (unsigned)cby[2], 0x04000000u); \
            int packed = (int)(__builtin_amdgcn_perm(t23, t01, 0x07060100u)      \
                               ^ 0x80808080u);  /* code - 128 per byte */        \
            *(int*)(pcs + (16*cb + n)*144 + trow + 4*quad) = packed;             \
        }                                                                        \
    }                                                                            \
    __syncthreads();                                                             \
    {                                                                            \
        v4i a0 = *(const v4i*)(pcs + (16*w + n)*144 + 16*quad);                  \
        v4i a1 = *(const v4i*)(pcs + (16*w + n)*144 + 64 + 16*quad);             \
        v4i c1a = MFMA16(a0, ones, vzero);                                       \
        c1a = MFMA16(a1, ones, c1a);                                             \
        float c1f[4];                                                            \
        _Pragma("unroll")                                                        \
        for (int r = 0; r < 4; ++r) c1f[r] = (float)c1a[r];                      \
        _Pragma("unroll")                                                        \
        for (int db = 0; db < 8; ++db) {                                         \
            v4i b0 = *(const v4i*)(v8s + (16*db + n)*144 + 16*quad);             \
            v4i b1 = *(const v4i*)(v8s + (16*db + n)*144 + 64 + 16*quad);        \
            v4i cv = MFMA16(a0, b0, vzero);                                      \
            cv = MFMA16(a1, b1, cv);                                             \
            v4i ga = MFMA16(ones, b0, vzero);  /* tile V col-sum (per d) */      \
            ga = MFMA16(ones, b1, ga);                                           \
            int d = 16*db + n;                                                   \
            float vs = vsA[d], vm = vsB[d];                                      \
            float gsum = (float)ga[0];                                           \
            cgsr[db] = fmaf(128.0f*vs, gsum, fmaf(16384.0f, vm, cgsr[db]));      \
            vsr[db]  = fmaf(vs, gsum, fmaf(128.0f, vm, vsr[db]));                \
            _Pragma("unroll")                                                    \
            for (int r = 0; r < 4; ++r)                                          \
                outa[r][db] = fmaf(vs, (float)cv[r],                             \
                                   fmaf(vm, c1f[r], outa[r][db]));               \
        }                                                                        \
    }                                                                            \
  } while (0)

    {
        int kt;
        for (kt = 0; kt < kt_end; ++kt) P2_TILE(false);
        kt = kt_end;
        if (causal) P2_TILE(true); else P2_TILE(false);
    }

    // ---- epilogue: out = psc*(outa + cgs) + pmin*vsum ----
    // (vsr covers groups <= kt_end; pmin != 0 only when kt_end==15, so exact.)
    float pscr[4], pmnr[4];
    #pragma unroll
    for (int r = 0; r < 4; ++r) {
        int qq = 16*w + 4*quad + r;
        pscr[r] = rs_psc[qq]; pmnr[r] = rs_pmn[qq];
    }
    #pragma unroll
    for (int db = 0; db < 8; ++db) {
        int d = 16*db + n;
        #pragma unroll
        for (int r = 0; r < 4; ++r) {
            int s = s0 + 16*w + 4*quad + r;
            OUT[(size_t)s*RSTR + boff + d] = fmaf(pscr[r], outa[r][db] + cgsr[db], pmnr[r]*vsr[db]);
        }
    }
}

extern "C" void kernel_launch(void* const* d_in, const int* in_sizes, int n_in,
                              void* d_out, int out_size, void* d_ws, size_t ws_size,
                              hipStream_t stream) {
    (void)in_sizes; (void)n_in; (void)out_size; (void)ws_size;
    const float* Q   = (const float*)d_in[0];
    const float* K   = (const float*)d_in[1];
    const float* V   = (const float*)d_in[2];
    const float* QMN = (const float*)d_in[3];
    const float* QSC = (const float*)d_in[4];
    const float* KMN = (const float*)d_in[5];
    const float* KSC = (const float*)d_in[6];
    const float* VMN = (const float*)d_in[7];
    const float* VSC = (const float*)d_in[8];
    const int*   CS  = (const int*)d_in[9];
    float* out = (float*)d_out;

    char* ws = (char*)d_ws;
    signed char* K8  = (signed char*)(ws + WS_K8);
    signed char* V8T = (signed char*)(ws + WS_V8T);

    prep_v<<<512, 256, 0, stream>>>(V, V8T);
    prep_k<<<1024, 256, 0, stream>>>(K, K8);
    attn_main<<<1024, 256, 0, stream>>>(Q, K8, V8T, QMN, QSC, KMN, KSC, VMN, VSC,
                                        CS, out);
}

// Round 5
// 243.285 us; speedup vs baseline: 1.1026x; 1.0436x over previous
//
#include <hip/hip_runtime.h>
#include <math.h>

// Quantized causal attention on int8 MFMA — R11.
// R10 post-mortem: lean prep WORKED (gap 130->118us) but MFMA-ones sums in
// the per-tile path added dependent latency (attn 127->136). Five-round
// tally: best attn = R0 exact structure (118.5us); best prep = R10 lean.
// R11 combines the proven halves, nothing new:
//  1. attn_main = R0 verbatim (separate k8s/v8s 60KB LDS, 2-barrier P1,
//     3-barrier P2, hoisted qb0/qb1, (256,2), SKs/ktC + GSV consumed).
//     ONE retained R10 element: rs_c3 via a single qsum-MFMA pair (once per
//     block, off the tile path) -> prep never reads Q (-16MB).
//  2. prep_k: streaming K pack + inline SKs (5 shfl per token, amortized
//     over 8 float4/thread). prep_v: R0 transpose + GSV epilogue verbatim.
// Tripwires: attn_main in [115,123]us, WRITE_SIZE ~32.8MB, gap <= 128us.

#define S_LEN 2048
#define BATCH 2
#define NH    16
#define HD    128
#define RSTR  4096   // floats between seq positions
#define SCALE2 (0.08838834764831845f * 1.4426950408889634f)   // (1/sqrt(128))/ln2
#define EXP2F(x) __builtin_amdgcn_exp2f(x)

typedef int v4i __attribute__((ext_vector_type(4)));
#define MFMA16(a,b,c) __builtin_amdgcn_mfma_i32_16x16x64_i8((a),(b),(c),0,0,0)

// ws byte offsets
#define WS_K8   0u
#define WS_V8T  (8u*1024u*1024u)
#define WS_SK   (16u*1024u*1024u)
#define WS_GSV  (WS_SK + 256u*1024u)

__device__ __forceinline__ int sbsum(unsigned p) {
    return (int)(signed char)(p) + (int)(signed char)(p>>8)
         + (int)(signed char)(p>>16) + (int)(signed char)(p>>24);
}

// ---- prep_k: streaming float->int8 pack of K + per-token sums SKs ----
__global__ __launch_bounds__(256) void prep_k(const float* __restrict__ K,
                                              signed char* __restrict__ K8,
                                              float* __restrict__ SKs)
{
    const int base = blockIdx.x*2048 + threadIdx.x;   // 1024 blocks x 256 x 8
    #pragma unroll
    for (int rep = 0; rep < 8; ++rep) {
        int idx = base + rep*256;                     // float4 index
        float4 x = *(const float4*)(K + (size_t)idx*4);
        int a=(int)x.x, b=(int)x.y, c=(int)x.z, d=(int)x.w;
        ((int*)K8)[idx] = (a&255)|((b&255)<<8)|((c&255)<<16)|((d&255)<<24);
        float s = x.x + x.y + x.z + x.w;
        #pragma unroll
        for (int off = 16; off >= 1; off >>= 1) s += __shfl_xor(s, off);
        if ((threadIdx.x & 31) == 0) SKs[idx >> 5] = s;
    }
}

// ---- prep_v: V transpose to [bh][d][t] int8 + GSV group sums ----
__global__ __launch_bounds__(256) void prep_v(const float* __restrict__ V,
                                              signed char* __restrict__ V8T,
                                              float* __restrict__ GSV)
{
    __shared__ int v8i[128*33];
    const int tid = threadIdx.x;
    const int bid = blockIdx.x;                 // 512 blocks
    const int bh = bid & 31, ck = bid >> 5;     // ck = 128-t chunk = v-group
    const int b = bh >> 4, h = bh & 15;
    const int t0 = ck * 128;
    const int boff = b*2048 + h*128;
    #pragma unroll
    for (int it = 0; it < 16; ++it) {
        int idx = tid + it*256;
        int t = idx >> 5, dw = idx & 31;
        float4 x = *(const float4*)(V + (size_t)(t0+t)*RSTR + boff + 4*dw);
        int a=(int)x.x, b2=(int)x.y, c=(int)x.z, d=(int)x.w;
        v8i[t*33 + dw] = (a&255)|((b2&255)<<8)|((c&255)<<16)|((d&255)<<24);
    }
    __syncthreads();
    #pragma unroll
    for (int it = 0; it < 4; ++it) {
        int j = tid + it*256;
        int tg = j & 31, dw = j >> 5;
        unsigned r0 = (unsigned)v8i[(4*tg+0)*33 + dw];
        unsigned r1 = (unsigned)v8i[(4*tg+1)*33 + dw];
        unsigned r2 = (unsigned)v8i[(4*tg+2)*33 + dw];
        unsigned r3 = (unsigned)v8i[(4*tg+3)*33 + dw];
        unsigned x01 = __builtin_amdgcn_perm(r1, r0, 0x05010400u);
        unsigned x23 = __builtin_amdgcn_perm(r3, r2, 0x05010400u);
        unsigned y01 = __builtin_amdgcn_perm(r1, r0, 0x07030602u);
        unsigned y23 = __builtin_amdgcn_perm(r3, r2, 0x07030602u);
        unsigned p[4];
        p[0] = __builtin_amdgcn_perm(x23, x01, 0x05040100u);
        p[1] = __builtin_amdgcn_perm(x23, x01, 0x07060302u);
        p[2] = __builtin_amdgcn_perm(y23, y01, 0x05040100u);
        p[3] = __builtin_amdgcn_perm(y23, y01, 0x07060302u);
        int s[4];
        #pragma unroll
        for (int jj = 0; jj < 4; ++jj) {
            int d = 4*dw + jj;
            *(int*)(V8T + ((size_t)bh*128 + d)*2048 + t0 + 4*tg) = (int)p[jj];
            s[jj] = sbsum(p[jj]);
        }
        #pragma unroll
        for (int off = 1; off < 32; off <<= 1) {
            #pragma unroll
            for (int jj = 0; jj < 4; ++jj) s[jj] += __shfl_xor(s[jj], off);
        }
        if (tg == 0) {
            #pragma unroll
            for (int jj = 0; jj < 4; ++jj)
                GSV[((size_t)bh*16 + ck)*128 + 4*dw + jj] = (float)s[jj];
        }
    }
}

// ---- main kernel (R0 structure) ----
__global__ __launch_bounds__(256, 2) void attn_main(
    const float* __restrict__ Q,
    const signed char* __restrict__ K8, const signed char* __restrict__ V8T,
    const float* __restrict__ QMN, const float* __restrict__ QSC,
    const float* __restrict__ KMN, const float* __restrict__ KSC,
    const float* __restrict__ VMN, const float* __restrict__ VSC,
    const float* __restrict__ SKs, const float* __restrict__ GSV,
    const int* __restrict__ CAUSAL, float* __restrict__ OUT)
{
    __shared__ __align__(16) signed char q8s[64*144];   // [q][d] int8
    __shared__ __align__(16) signed char k8s[128*144];  // [t][d] int8 (phase 1 only)
    __shared__ __align__(16) signed char v8s[128*144];  // [d][t] int8 (transposed)
    __shared__ __align__(16) signed char pcs[64*144];   // [q][t] code' int8
    __shared__ float rs_c1[64], rs_c2[64], rs_c3[64];
    __shared__ float rs_mx[64], rs_den[64], rs_mn[64];
    __shared__ float rs_u1[64], rs_w1[64], rs_psc[64], rs_pmn[64];
    __shared__ float ktA[128], ktB[128], ktC[128];      // ks*S2, km*S2, sk8
    __shared__ float vsA[128], vsB[128];                // vs, vm (current group)
    __shared__ float vsumL[128], cgsL[128];             // in-block VSUM / CGS row

    const int tid  = threadIdx.x;
    const int w    = tid >> 6;
    const int lane = tid & 63;
    const int n    = lane & 15;
    const int quad = lane >> 4;
    const int bhi  = blockIdx.x & 31;
    const int qt   = 31 - (int)(blockIdx.x >> 5);   // heavy tiles first
    const int b    = bhi >> 4, h = bhi & 15;
    const int causal = *CAUSAL;
    const int s0   = qt * 64;
    const int boff = b*2048 + h*128;
    const v4i vzero = {0,0,0,0};
    const v4i ones  = {0x01010101,0x01010101,0x01010101,0x01010101};

    // ---- stage Q tile (float -> int8 LDS) + per-row consts ----
    #pragma unroll
    for (int it = 0; it < 8; ++it) {
        int idx = tid + it*256;
        int row = idx >> 5, d4 = (idx & 31) << 2;
        float4 x = *(const float4*)(Q + (size_t)(s0+row)*RSTR + boff + d4);
        int a=(int)x.x, b2=(int)x.y, c=(int)x.z, d=(int)x.w;
        *(int*)(q8s + row*144 + d4) = (a&255)|((b2&255)<<8)|((c&255)<<16)|((d&255)<<24);
    }
    if (tid < 64) {
        int si = (s0 + tid)*32 + bhi;
        rs_c1[tid] = QSC[si]; rs_c2[tid] = QMN[si];
    }
    __syncthreads();

    const int kt_end = causal ? ((s0 + 63) >> 7) : 15;

    v4i a0p = *(const v4i*)(q8s + (16*w + n)*144 + 16*quad);
    v4i a1p = *(const v4i*)(q8s + (16*w + n)*144 + 64 + 16*quad);

    // Q token sums via one MFMA-ones pair -> rs_c3 (replaces prep SQs pass)
    {
        v4i qsum = MFMA16(a0p, ones, vzero);
        qsum = MFMA16(a1p, ones, qsum);
        if (n == 0) {
            #pragma unroll
            for (int r = 0; r < 4; ++r) {
                int qq = 16*w + 4*quad + r;
                rs_c3[qq] = fmaf(rs_c1[qq], (float)qsum[r], 128.0f*rs_c2[qq]);
            }
        }
    }
    __syncthreads();

    float c1r[4], c2r[4], c3r[4]; int qgr[4];
    #pragma unroll
    for (int r = 0; r < 4; ++r) {
        int qq = 16*w + 4*quad + r;
        c1r[r] = rs_c1[qq]; c2r[r] = rs_c2[qq]; c3r[r] = rs_c3[qq];
        qgr[r] = s0 + qq;
    }

    float m[4], l[4], mn[4];
    #pragma unroll
    for (int r = 0; r < 4; ++r) { m[r] = -INFINITY; l[r] = 0.f; mn[r] = INFINITY; }

    // ================= Phase 1: softmax stats (log2 domain) =================
#define P1_TILE(MASKED)                                                          \
  do {                                                                           \
    const int t0g = kt * 128;                                                    \
    __syncthreads();                                                             \
    _Pragma("unroll")                                                            \
    for (int it = 0; it < 4; ++it) {                                             \
        int idx = tid + it*256;                                                  \
        int trow = idx >> 3, doff = (idx & 7) << 4;                              \
        *(uint4*)(k8s + trow*144 + doff) =                                       \
            *(const uint4*)(K8 + ((size_t)(t0g+trow)*32 + bhi)*128 + doff);      \
    }                                                                            \
    if (tid < 128) {                                                             \
        int si = (t0g + tid)*32 + bhi;                                           \
        ktA[tid] = KSC[si]*SCALE2; ktB[tid] = KMN[si]*SCALE2; ktC[tid] = SKs[si];\
    }                                                                            \
    __syncthreads();                                                             \
    float tmax[4], sarr[8][4];                                                   \
    _Pragma("unroll")                                                            \
    for (int r = 0; r < 4; ++r) tmax[r] = -INFINITY;                             \
    _Pragma("unroll")                                                            \
    for (int tb = 0; tb < 8; ++tb) {                                             \
        v4i b0 = *(const v4i*)(k8s + (16*tb + n)*144 + 16*quad);                 \
        v4i b1 = *(const v4i*)(k8s + (16*tb + n)*144 + 64 + 16*quad);            \
        v4i acc = MFMA16(a0p, b0, vzero);                                        \
        acc = MFMA16(a1p, b1, acc);                                              \
        int tl = 16*tb + n;                                                      \
        float kA = ktA[tl], kB = ktB[tl], kC = ktC[tl];                          \
        _Pragma("unroll")                                                        \
        for (int r = 0; r < 4; ++r) {                                            \
            float Sf = (float)acc[r];                                            \
            float sv = fmaf(kA, fmaf(c1r[r], Sf, c2r[r]*kC), kB*c3r[r]);         \
            if (MASKED) sv = (t0g + tl > qgr[r]) ? -INFINITY : sv;               \
            sarr[tb][r] = sv;                                                    \
            tmax[r] = fmaxf(tmax[r], sv);                                        \
            mn[r] = fminf(mn[r], sv);                                            \
        }                                                                        \
    }                                                                            \
    _Pragma("unroll")                                                            \
    for (int r = 0; r < 4; ++r) {                                                \
        float mm = fmaxf(m[r], tmax[r]);                                         \
        if (mm > -INFINITY) {                                                    \
            float e0 = EXP2F(sarr[0][r]-mm) + EXP2F(sarr[1][r]-mm);              \
            float e1 = EXP2F(sarr[2][r]-mm) + EXP2F(sarr[3][r]-mm);              \
            float e2 = EXP2F(sarr[4][r]-mm) + EXP2F(sarr[5][r]-mm);              \
            float e3 = EXP2F(sarr[6][r]-mm) + EXP2F(sarr[7][r]-mm);              \
            l[r] = fmaf(l[r], EXP2F(m[r]-mm), (e0+e1)+(e2+e3));                  \
            m[r] = mm;                                                           \
        }                                                                        \
    }                                                                            \
  } while (0)

    {
        int kt;
        for (kt = 0; kt < kt_end; ++kt) P1_TILE(false);
        kt = kt_end;
        if (causal) P1_TILE(true); else P1_TILE(false);
    }

    // reduce stats across the 16 col-lanes
    #pragma unroll
    for (int r = 0; r < 4; ++r) {
        #pragma unroll
        for (int off = 1; off < 16; off <<= 1) {
            float m2 = __shfl_xor(m[r], off);
            float l2 = __shfl_xor(l[r], off);
            float n2 = __shfl_xor(mn[r], off);
            float mm = fmaxf(m[r], m2);
            if (mm > -INFINITY) l[r] = l[r]*EXP2F(m[r]-mm) + l2*EXP2F(m2-mm);
            m[r] = mm;
            mn[r] = fminf(mn[r], n2);
        }
        if (n == 0) {
            int qq = 16*w + 4*quad + r;
            rs_mx[qq] = m[r]; rs_den[qq] = l[r]; rs_mn[qq] = mn[r];
        }
    }
    __syncthreads();
    if (tid < 64) {
        float mx = rs_mx[tid], den = rs_den[tid], mnv = rs_mn[tid];
        float invd = 1.0f/den;
        int s = s0 + tid;
        bool hasmask = (causal != 0) && (s < S_LEN-1);
        float pmin = hasmask ? 0.0f : EXP2F(mnv - mx)*invd;
        float psc  = (invd - pmin)/255.0f + 1e-12f;
        float ipsc = 1.0f/psc;
        rs_u1[tid] = invd*ipsc; rs_w1[tid] = -pmin*ipsc;
        rs_psc[tid] = psc; rs_pmn[tid] = pmin;
    } else if (tid >= 128) {
        // in-block VSUM (full row) + CGS (cumulative to kt_end) for this bh
        int d = tid - 128;
        float vsum = 0.f, cgs = 0.f;
        #pragma unroll
        for (int g = 0; g < 16; ++g) {
            float gs = GSV[((size_t)bhi*16 + g)*128 + d];
            int vi = ((g*BATCH + b)*NH + h)*HD + d;
            float vs = VSC[vi], vm = VMN[vi];
            vsum = fmaf(vs, gs, fmaf(128.0f, vm, vsum));
            if (g <= kt_end) cgs = fmaf(128.0f*vs, gs, fmaf(16384.0f, vm, cgs));
        }
        vsumL[d] = vsum; cgsL[d] = cgs;
    }
    __syncthreads();

    // ---- hoist P2 tile-invariants: Q B-fragments + per-q constants ----
    v4i qb0[4], qb1[4];
    float qc1[4], qc2[4], qc3[4], qmxn[4], qu1[4], qw1[4];
    int qgq[4];
    #pragma unroll
    for (int cb = 0; cb < 4; ++cb) {
        int qcol = 16*cb + n;
        qb0[cb] = *(const v4i*)(q8s + qcol*144 + 16*quad);
        qb1[cb] = *(const v4i*)(q8s + qcol*144 + 64 + 16*quad);
        qc1[cb] = rs_c1[qcol]; qc2[cb] = rs_c2[qcol]; qc3[cb] = rs_c3[qcol];
        qmxn[cb] = -rs_mx[qcol]; qu1[cb] = rs_u1[qcol]; qw1[cb] = rs_w1[qcol];
        qgq[cb] = s0 + qcol;
    }

    // ================= Phase 2: requant + PV =================
    float outa[4][8];
    #pragma unroll
    for (int r = 0; r < 4; ++r)
        #pragma unroll
        for (int db = 0; db < 8; ++db) outa[r][db] = 0.f;

#define P2_TILE(MASKED)                                                          \
  do {                                                                           \
    const int t0g = kt * 128;                                                    \
    __syncthreads();   /* previous PV reads of v8s/pcs done */                   \
    _Pragma("unroll")                                                            \
    for (int it = 0; it < 4; ++it) {                                             \
        int idx = tid + it*256;                                                  \
        int trow = idx >> 3, doff = (idx & 7) << 4;                              \
        *(uint4*)(v8s + trow*144 + doff) =                                       \
            *(const uint4*)(V8T + ((size_t)bhi*128 + trow)*2048 + t0g + doff);   \
    }                                                                            \
    if (tid < 128) {                                                             \
        int si = (t0g + tid)*32 + bhi;                                           \
        ktA[tid] = KSC[si]*SCALE2; ktB[tid] = KMN[si]*SCALE2; ktC[tid] = SKs[si];\
    } else {                                                                     \
        int d = tid - 128;                                                       \
        int vi = ((kt*BATCH + b)*NH + h)*HD + d;                                 \
        vsA[d] = VSC[vi]; vsB[d] = VMN[vi];                                      \
    }                                                                            \
    __syncthreads();                                                             \
    _Pragma("unroll")                                                            \
    for (int rb = 0; rb < 2; ++rb) {                                             \
        int trow = 32*w + 16*rb;                                                 \
        const signed char* kp = K8 + ((size_t)(t0g+trow+n)*32 + bhi)*128         \
                                   + 16*quad;                                    \
        v4i a0 = *(const v4i*)kp;          /* A-operand direct from global */    \
        v4i a1 = *(const v4i*)(kp + 64);                                         \
        float ksr[4], kmr[4], skr[4];                                            \
        int tgb = t0g + trow + 4*quad;                                           \
        _Pragma("unroll")                                                        \
        for (int r = 0; r < 4; ++r) {                                            \
            int tl = trow + 4*quad + r;                                          \
            ksr[r] = ktA[tl]; kmr[r] = ktB[tl]; skr[r] = ktC[tl];                \
        }                                                                        \
        _Pragma("unroll")                                                        \
        for (int cb = 0; cb < 4; ++cb) {                                         \
            v4i acc = MFMA16(a0, qb0[cb], vzero);                                \
            acc = MFMA16(a1, qb1[cb], acc);                                      \
            int cby[4];                                                          \
            _Pragma("unroll")                                                    \
            for (int r = 0; r < 4; ++r) {                                        \
                float Sf = (float)acc[r];                                        \
                float x = fmaf(ksr[r], fmaf(qc1[cb], Sf, qc2[cb]*skr[r]),        \
                               fmaf(kmr[r], qc3[cb], qmxn[cb]));                 \
                if (MASKED) x = (tgb + r > qgq[cb]) ? -INFINITY : x;             \
                float e = EXP2F(x);                                              \
                float f = fmaf(e, qu1[cb], qw1[cb]) + 8388608.0f; /* RNE int */  \
                cby[r] = __float_as_int(f);                                      \
            }                                                                    \
            unsigned t01 = __builtin_amdgcn_perm((unsigned)cby[1],               \
                                                 (unsigned)cby[0], 0x00000400u); \
            unsigned t23 = __builtin_amdgcn_perm((unsigned)cby[3],               \
                                                 (unsigned)cby[2], 0x04000000u); \
            int packed = (int)(__builtin_amdgcn_perm(t23, t01, 0x07060100u)      \
                               ^ 0x80808080u);  /* code - 128 per byte */        \
            *(int*)(pcs + (16*cb + n)*144 + trow + 4*quad) = packed;             \
        }                                                                        \
    }                                                                            \
    __syncthreads();                                                             \
    {                                                                            \
        v4i a0 = *(const v4i*)(pcs + (16*w + n)*144 + 16*quad);                  \
        v4i a1 = *(const v4i*)(pcs + (16*w + n)*144 + 64 + 16*quad);             \
        v4i c1a = MFMA16(a0, ones, vzero);                                       \
        c1a = MFMA16(a1, ones, c1a);                                             \
        float c1f[4];                                                            \
        _Pragma("unroll")                                                        \
        for (int r = 0; r < 4; ++r) c1f[r] = (float)c1a[r];                      \
        _Pragma("unroll")                                                        \
        for (int db = 0; db < 8; ++db) {                                         \
            v4i b0 = *(const v4i*)(v8s + (16*db + n)*144 + 16*quad);             \
            v4i b1 = *(const v4i*)(v8s + (16*db + n)*144 + 64 + 16*quad);        \
            v4i cv = MFMA16(a0, b0, vzero);                                      \
            cv = MFMA16(a1, b1, cv);                                             \
            int d = 16*db + n;                                                   \
            float vs = vsA[d], vm = vsB[d];                                      \
            _Pragma("unroll")                                                    \
            for (int r = 0; r < 4; ++r)                                          \
                outa[r][db] = fmaf(vs, (float)cv[r],                             \
                                   fmaf(vm, c1f[r], outa[r][db]));               \
        }                                                                        \
    }                                                                            \
  } while (0)

    {
        int kt;
        for (kt = 0; kt < kt_end; ++kt) P2_TILE(false);
        kt = kt_end;
        if (causal) P2_TILE(true); else P2_TILE(false);
    }

    // ---- epilogue: out = psc*(outa + cgs) + pmin*vsum ----
    float pscr[4], pmnr[4];
    #pragma unroll
    for (int r = 0; r < 4; ++r) {
        int qq = 16*w + 4*quad + r;
        pscr[r] = rs_psc[qq]; pmnr[r] = rs_pmn[qq];
    }
    #pragma unroll
    for (int db = 0; db < 8; ++db) {
        int d = 16*db + n;
        float vsum = vsumL[d];
        float cgs  = cgsL[d];
        #pragma unroll
        for (int r = 0; r < 4; ++r) {
            int s = s0 + 16*w + 4*quad + r;
            OUT[(size_t)s*RSTR + boff + d] = fmaf(pscr[r], outa[r][db] + cgs, pmnr[r]*vsum);
        }
    }
}

extern "C" void kernel_launch(void* const* d_in, const int* in_sizes, int n_in,
                              void* d_out, int out_size, void* d_ws, size_t ws_size,
                              hipStream_t stream) {
    (void)in_sizes; (void)n_in; (void)out_size; (void)ws_size;
    const float* Q   = (const float*)d_in[0];
    const float* K   = (const float*)d_in[1];
    const float* V   = (const float*)d_in[2];
    const float* QMN = (const float*)d_in[3];
    const float* QSC = (const float*)d_in[4];
    const float* KMN = (const float*)d_in[5];
    const float* KSC = (const float*)d_in[6];
    const float* VMN = (const float*)d_in[7];
    const float* VSC = (const float*)d_in[8];
    const int*   CS  = (const int*)d_in[9];
    float* out = (float*)d_out;

    char* ws = (char*)d_ws;
    signed char* K8  = (signed char*)(ws + WS_K8);
    signed char* V8T = (signed char*)(ws + WS_V8T);
    float* SKs  = (float*)(ws + WS_SK);
    float* GSVp = (float*)(ws + WS_GSV);

    prep_v<<<512, 256, 0, stream>>>(V, V8T, GSVp);
    prep_k<<<1024, 256, 0, stream>>>(K, K8, SKs);
    attn_main<<<1024, 256, 0, stream>>>(Q, K8, V8T, QMN, QSC, KMN, KSC, VMN, VSC,
                                        SKs, GSVp, CS, out);
}